// Round 3
// baseline (249.851 us; speedup 1.0000x reference)
//
#include <hip/hip_runtime.h>
#include <hip/hip_fp16.h>

// ---------------------------------------------------------------------------
// score = relu(relu([h[src]|h[dst]]W1+b1)W2+b2)W3+b3
// NEW PATH (ws >= 51.3MB):
//   P = h@W1_top (fp16), Q = h@W1_bot + b1 (fp16)  -- per-NODE precompute
//   edge kernel: B-frag = relu(P16[src]+Q16[dst]) gathered per-lane (16B),
//   layer2 MFMA from VGPR weights, layer3 MFMA from in-register fragments
//   (perm3), 512B LDS cross-wave reduce, 1 barrier/tile, no big LDS tiles.
// FALLBACK (small ws): round-1 kernel, f32 gather path (needs 100KB ws).
// ---------------------------------------------------------------------------

typedef _Float16 half8 __attribute__((ext_vector_type(8)));
typedef _Float16 half4_t __attribute__((ext_vector_type(4)));
typedef float    f32x4 __attribute__((ext_vector_type(4)));

#define MFMA16(a, b, c) __builtin_amdgcn_mfma_f32_16x16x32_f16((a), (b), (c), 0, 0, 0)

#define N_NODES_C 100000
#define N_EDGES_C 800000

// ---- new-path ws layout ----
#define W1PF_OFF  0         // 32KB  A-frags of W1_top^T
#define W1QF_OFF  32768     // 32KB  A-frags of W1_bot^T
#define W2F_OFF_N 65536     // 32KB  A-frags of W2^T
#define W3F_OFF_N 98304     // 4KB   A-frags of W3^T (perm3)
#define P16_OFF   131072
#define TBL_HALVES (N_NODES_C * 128)            // 12.8M halves
#define Q16_OFF   (P16_OFF + TBL_HALVES * 2)
#define WS_NEED_NEW ((size_t)Q16_OFF + (size_t)TBL_HALVES * 2)   // ~51.3MB

#define ET 32                       // edges per tile (new edge kernel)
#define NT_E (N_EDGES_C / ET)       // 25000
#define GRID_E 1536
#define NT_N ((N_NODES_C + 63) / 64)  // 1563

// =========================== NEW PATH ======================================

// A-frag pack: frag (cm,kk): lane=16g+rr elem j -> W[32kk+8g+j][16cm+rr]
// w3f uses perm3(g,j)=4g+(j&3)+16*(j>>2) (shared by B-side built in-register).
__global__ void pack_w_new(const float* __restrict__ W1, const float* __restrict__ W2,
                           const float* __restrict__ W3, char* __restrict__ wsb) {
    int i = blockIdx.x * blockDim.x + threadIdx.x;
    _Float16* w1pf = (_Float16*)(wsb + W1PF_OFF);
    _Float16* w1qf = (_Float16*)(wsb + W1QF_OFF);
    _Float16* w2f  = (_Float16*)(wsb + W2F_OFF_N);
    _Float16* w3f  = (_Float16*)(wsb + W3F_OFF_N);
    if (i < 16384) {
        int j = i & 7, lane = (i >> 3) & 63, kk = (i >> 9) & 3, cm = i >> 11;
        int g = lane >> 4, rr = lane & 15;
        int k = 32 * kk + 8 * g + j, n = 16 * cm + rr;
        w1pf[i] = (_Float16)W1[k * 128 + n];
        w1qf[i] = (_Float16)W1[(k + 128) * 128 + n];
        w2f[i]  = (_Float16)W2[k * 128 + n];
    }
    if (i < 2048) {
        int j = i & 7, lane = (i >> 3) & 63, t = i >> 9;
        int g = lane >> 4, rr = lane & 15;
        int k = 32 * t + 4 * g + (j & 3) + 16 * (j >> 2);
        w3f[i] = (rr < 2) ? (_Float16)W3[k * 2 + rr] : (_Float16)0.0f;
    }
}

// P = h@W1_top ; Q = h@W1_bot + b1 ; both stored fp16 row-major [node][128].
// 512 thr = 8 waves: wave w: table t=w>>2, chan-quad cmq=w&3 (cpw=32).
__global__ __launch_bounds__(512, 4) void pq_kernel(const float* __restrict__ h,
                                                    const float* __restrict__ b1,
                                                    char* __restrict__ wsb) {
    const int tid = threadIdx.x;
    const int w = tid >> 6, l = tid & 63, g = l >> 4, rr = l & 15;
    const int t = w >> 2, cmq = w & 3;
    const half8* wf = (const half8*)(wsb + (t ? W1QF_OFF : W1PF_OFF));
    half8 W1F[2][4];
#pragma unroll
    for (int cm = 0; cm < 2; ++cm)
#pragma unroll
        for (int kk = 0; kk < 4; ++kk)
            W1F[cm][kk] = wf[((2 * cmq + cm) * 4 + kk) * 64 + l];
    f32x4 b1v[2] = {{0.f, 0.f, 0.f, 0.f}, {0.f, 0.f, 0.f, 0.f}};
    if (t == 1) {
#pragma unroll
        for (int cm = 0; cm < 2; ++cm)
            b1v[cm] = *(const f32x4*)(b1 + 16 * (2 * cmq + cm) + 4 * g);
    }
    _Float16* tbl = (_Float16*)(wsb + (t ? Q16_OFF : P16_OFF));

    for (int tile = blockIdx.x; tile < NT_N; tile += gridDim.x) {
        f32x4 acc[2][4];
#pragma unroll
        for (int cm = 0; cm < 2; ++cm)
#pragma unroll
            for (int ce = 0; ce < 4; ++ce) acc[cm][ce] = f32x4{0.f, 0.f, 0.f, 0.f};
#pragma unroll
        for (int kk = 0; kk < 4; ++kk) {
#pragma unroll
            for (int ce = 0; ce < 4; ++ce) {
                int node = tile * 64 + 16 * ce + rr;
                if (node > N_NODES_C - 1) node = N_NODES_C - 1;
                const float4* hp = (const float4*)(h + (size_t)node * 128 + kk * 32 + 8 * g);
                float4 fa = hp[0], fb = hp[1];
                half8 b;
                b[0] = (_Float16)fa.x; b[1] = (_Float16)fa.y;
                b[2] = (_Float16)fa.z; b[3] = (_Float16)fa.w;
                b[4] = (_Float16)fb.x; b[5] = (_Float16)fb.y;
                b[6] = (_Float16)fb.z; b[7] = (_Float16)fb.w;
                acc[0][ce] = MFMA16(W1F[0][kk], b, acc[0][ce]);
                acc[1][ce] = MFMA16(W1F[1][kk], b, acc[1][ce]);
            }
        }
#pragma unroll
        for (int cm = 0; cm < 2; ++cm)
#pragma unroll
            for (int ce = 0; ce < 4; ++ce) {
                int node = tile * 64 + 16 * ce + rr;
                if (node < N_NODES_C) {
                    f32x4 v = acc[cm][ce] + b1v[cm];
                    half4_t o;
                    o[0] = (_Float16)v[0]; o[1] = (_Float16)v[1];
                    o[2] = (_Float16)v[2]; o[3] = (_Float16)v[3];
                    *(half4_t*)(tbl + (size_t)node * 128 + 16 * (2 * cmq + cm) + 4 * g) = o;
                }
            }
    }
}

// Edge kernel: 128 thr = 2 waves; wave w owns layer-2 chans [64w,64w+64).
// 32-edge tiles; per (kk,ce): two 16B gathers -> relu(p+q) -> 4 MFMA.
// Layer3: B-frags built from acc registers with perm3; 2 MFMA per ce;
// cross-wave reduce via 512B LDS, 1 barrier/tile (double-buffered).
__global__ __launch_bounds__(128, 3) void edge_kernel(
    const int* __restrict__ src, const int* __restrict__ dst,
    const float* __restrict__ b2, const float* __restrict__ b3,
    const char* __restrict__ wsb, float* __restrict__ out) {
    __shared__ float2 part[2][2][16];
    const int tid = threadIdx.x;
    const int w = tid >> 6, l = tid & 63, g = l >> 4, rr = l & 15;
    const half8* w2f = (const half8*)(wsb + W2F_OFF_N);
    const half8* w3f = (const half8*)(wsb + W3F_OFF_N);
    const half8* P16 = (const half8*)(wsb + P16_OFF);   // row = 16 chunks of 16B
    const half8* Q16 = (const half8*)(wsb + Q16_OFF);

    half8 W2F[4][4], W3F[2];
#pragma unroll
    for (int cm = 0; cm < 4; ++cm)
#pragma unroll
        for (int kk = 0; kk < 4; ++kk)
            W2F[cm][kk] = w2f[((4 * w + cm) * 4 + kk) * 64 + l];
    W3F[0] = w3f[(2 * w) * 64 + l];
    W3F[1] = w3f[(2 * w + 1) * 64 + l];

    half4_t b2h[4];
#pragma unroll
    for (int cm = 0; cm < 4; ++cm) {
        f32x4 bv = *(const f32x4*)(b2 + 16 * (4 * w + cm) + 4 * g);
        b2h[cm][0] = (_Float16)bv[0]; b2h[cm][1] = (_Float16)bv[1];
        b2h[cm][2] = (_Float16)bv[2]; b2h[cm][3] = (_Float16)bv[3];
    }
    const float b30 = b3[0], b31 = b3[1];

    int tile = blockIdx.x;
    int sc0 = src[tile * ET + rr],      sc1 = src[tile * ET + 16 + rr];
    int dc0 = dst[tile * ET + rr],      dc1 = dst[tile * ET + 16 + rr];
    int par = 0;

    for (; tile < NT_E; tile += GRID_E) {
        int ntile = tile + GRID_E; if (ntile >= NT_E) ntile = NT_E - 1;
        f32x4 acc[4][2];
#pragma unroll
        for (int cm = 0; cm < 4; ++cm) {
            acc[cm][0] = f32x4{0.f, 0.f, 0.f, 0.f};
            acc[cm][1] = f32x4{0.f, 0.f, 0.f, 0.f};
        }
        const half8* pr0 = P16 + (size_t)sc0 * 16 + g;
        const half8* pr1 = P16 + (size_t)sc1 * 16 + g;
        const half8* qr0 = Q16 + (size_t)dc0 * 16 + g;
        const half8* qr1 = Q16 + (size_t)dc1 * 16 + g;
        const half8 hz = {0, 0, 0, 0, 0, 0, 0, 0};
#pragma unroll
        for (int kk = 0; kk < 4; ++kk) {
            {
                half8 p = pr0[4 * kk], q = qr0[4 * kk];
                half8 b = __builtin_elementwise_max(p + q, hz);
                acc[0][0] = MFMA16(W2F[0][kk], b, acc[0][0]);
                acc[1][0] = MFMA16(W2F[1][kk], b, acc[1][0]);
                acc[2][0] = MFMA16(W2F[2][kk], b, acc[2][0]);
                acc[3][0] = MFMA16(W2F[3][kk], b, acc[3][0]);
            }
            {
                half8 p = pr1[4 * kk], q = qr1[4 * kk];
                half8 b = __builtin_elementwise_max(p + q, hz);
                acc[0][1] = MFMA16(W2F[0][kk], b, acc[0][1]);
                acc[1][1] = MFMA16(W2F[1][kk], b, acc[1][1]);
                acc[2][1] = MFMA16(W2F[2][kk], b, acc[2][1]);
                acc[3][1] = MFMA16(W2F[3][kk], b, acc[3][1]);
            }
        }
        // prefetch next-tile indices (latency hidden under layer3 + store)
        int sn0 = src[ntile * ET + rr], sn1 = src[ntile * ET + 16 + rr];
        int dn0 = dst[ntile * ET + rr], dn1 = dst[ntile * ET + 16 + rr];

        // ---- layer 3 in-register: chans of this wave = 64w + 32tl + perm3(g,j)
        f32x4 D3[2] = {{0.f, 0.f, 0.f, 0.f}, {0.f, 0.f, 0.f, 0.f}};
#pragma unroll
        for (int tl = 0; tl < 2; ++tl)
#pragma unroll
            for (int ce = 0; ce < 2; ++ce) {
                half8 bf;
#pragma unroll
                for (int j = 0; j < 8; ++j) {
                    const int cm = 2 * tl + (j >> 2), r = j & 3;
                    float v = acc[cm][ce][r] + (float)b2h[cm][r];
                    v = v > 0.f ? v : 0.f;
                    bf[j] = (_Float16)v;
                }
                D3[ce] = MFMA16(W3F[tl], bf, D3[ce]);
            }
        // ---- cross-wave reduce (rows 0,1 live in lanes l<16, regs 0,1)
        if (w == 1 && l < 16) {
            part[par][0][rr] = make_float2(D3[0][0], D3[0][1]);
            part[par][1][rr] = make_float2(D3[1][0], D3[1][1]);
        }
        __syncthreads();
        if (w == 0 && l < 16) {
#pragma unroll
            for (int ce = 0; ce < 2; ++ce) {
                float2 pp = part[par][ce][rr];
                float2 ov;
                ov.x = D3[ce][0] + pp.x + b30;
                ov.y = D3[ce][1] + pp.y + b31;
                *(float2*)(out + (size_t)(tile * ET + 16 * ce + rr) * 2) = ov;
            }
        }
        par ^= 1;
        sc0 = sn0; sc1 = sn1; dc0 = dn0; dc1 = dn1;
    }
}

// =========================== FALLBACK (round-1, f32 gather) ================

#define NT_O   12500
#define GRID_O 512
#define OW1_OFF 0
#define OW2_OFF 65536
#define OW3_OFF 98304

__global__ void pack_w_old(const float* __restrict__ W1, const float* __restrict__ W2,
                           const float* __restrict__ W3, char* __restrict__ wsb) {
    int i = blockIdx.x * blockDim.x + threadIdx.x;
    _Float16* w1f = (_Float16*)(wsb + OW1_OFF);
    _Float16* w2f = (_Float16*)(wsb + OW2_OFF);
    _Float16* w3f = (_Float16*)(wsb + OW3_OFF);
    if (i < 32768) {
        int j = i & 7, lx = (i >> 3) & 63, kk = (i >> 9) & 7, t = i >> 12;
        int k = 32 * kk + 8 * (lx >> 4) + j, n = 16 * t + (lx & 15);
        w1f[i] = (_Float16)W1[k * 128 + n];
    }
    if (i < 16384) {
        int j = i & 7, lx = (i >> 3) & 63, kk = (i >> 9) & 3, t = i >> 11;
        int k = 32 * kk + 8 * (lx >> 4) + j, n = 16 * t + (lx & 15);
        w2f[i] = (_Float16)W2[k * 128 + n];
    }
    if (i < 2048) {
        int j = i & 7, lx = (i >> 3) & 63, kk = i >> 9;
        int k = 32 * kk + 8 * (lx >> 4) + j, n = lx & 15;
        w3f[i] = (n < 2) ? (_Float16)W3[k * 2 + n] : (_Float16)0.0f;
    }
}

__device__ inline half8 ldfrag_f32(const float* __restrict__ h, int idx, int kk, int g) {
    const float4* p = (const float4*)(h + (size_t)idx * 128 + (kk & 3) * 32 + g * 8);
    float4 a = p[0], b = p[1];
    half8 o;
    o[0] = (_Float16)a.x; o[1] = (_Float16)a.y; o[2] = (_Float16)a.z; o[3] = (_Float16)a.w;
    o[4] = (_Float16)b.x; o[5] = (_Float16)b.y; o[6] = (_Float16)b.z; o[7] = (_Float16)b.w;
    return o;
}

__global__ __launch_bounds__(256, 2) void edge_mlp_old(
    const float* __restrict__ h, const int* __restrict__ src, const int* __restrict__ dst,
    const float* __restrict__ b1, const float* __restrict__ b2, const float* __restrict__ b3,
    const char* __restrict__ wsb, float* __restrict__ out) {
    __shared__ half8 Xp [32 * 64];
    __shared__ half8 Y1p[16 * 64];
    __shared__ half8 Y2p[16 * 64];
    const int tid = threadIdx.x;
    const int w = tid >> 6, l = tid & 63;
    const int g = l >> 4, rr = l & 15;
    const int ghalf = rr >> 3, j7 = rr & 7;
    half8 W1F[2][8], W2F[2][4], W3F[4];
    {
        const half8* p1 = (const half8*)(wsb + OW1_OFF);
        const half8* p2 = (const half8*)(wsb + OW2_OFF);
        const half8* p3 = (const half8*)(wsb + OW3_OFF);
#pragma unroll
        for (int nt = 0; nt < 2; ++nt)
#pragma unroll
            for (int kk = 0; kk < 8; ++kk) W1F[nt][kk] = p1[((w * 2 + nt) * 8 + kk) * 64 + l];
#pragma unroll
        for (int nt = 0; nt < 2; ++nt)
#pragma unroll
            for (int kk = 0; kk < 4; ++kk) W2F[nt][kk] = p2[((w * 2 + nt) * 4 + kk) * 64 + l];
#pragma unroll
        for (int kk = 0; kk < 4; ++kk) W3F[kk] = p3[kk * 64 + l];
    }
    float b1r[2], b2r[2];
    b1r[0] = b1[w * 32 + rr];      b1r[1] = b1[w * 32 + 16 + rr];
    b2r[0] = b2[w * 32 + rr];      b2r[1] = b2[w * 32 + 16 + rr];
    const float b3r = (rr < 2) ? b3[rr] : 0.0f;
    _Float16* y1h = (_Float16*)Y1p;
    _Float16* y2h = (_Float16*)Y2p;
    int   idxn[8];
    half8 xt[8];
    int tile = blockIdx.x;
#pragma unroll
    for (int i = 0; i < 8; i++) {
        int bidx = w * 8 + i, kk = bidx >> 2;
        int e = ((i & 3) << 4) + rr;
        int id = (kk < 4 ? src : dst)[tile * 64 + e];
        xt[i] = ldfrag_f32(h, id, kk, g);
    }
#pragma unroll
    for (int i = 0; i < 8; i++) Xp[(w * 8 + i) * 64 + l] = xt[i];
    {
        int t1 = tile + GRID_O; if (t1 >= NT_O) t1 = NT_O - 1;
#pragma unroll
        for (int i = 0; i < 8; i++) {
            int bidx = w * 8 + i, kk = bidx >> 2;
            int e = ((i & 3) << 4) + rr;
            idxn[i] = (kk < 4 ? src : dst)[t1 * 64 + e];
        }
    }
    __syncthreads();
    for (; tile < NT_O; tile += GRID_O) {
        f32x4 acc1[4][2];
#pragma unroll
        for (int mt = 0; mt < 4; ++mt) {
            acc1[mt][0] = f32x4{0.f, 0.f, 0.f, 0.f};
            acc1[mt][1] = f32x4{0.f, 0.f, 0.f, 0.f};
        }
#pragma unroll
        for (int kk = 0; kk < 8; ++kk) {
            half8 a[4];
#pragma unroll
            for (int mt = 0; mt < 4; ++mt) a[mt] = Xp[(kk * 4 + mt) * 64 + l];
#pragma unroll
            for (int mt = 0; mt < 4; ++mt) {
                acc1[mt][0] = MFMA16(a[mt], W1F[0][kk], acc1[mt][0]);
                acc1[mt][1] = MFMA16(a[mt], W1F[1][kk], acc1[mt][1]);
            }
        }
#pragma unroll
        for (int i = 0; i < 8; i++) {
            int kk = (w * 8 + i) >> 2;
            xt[i] = ldfrag_f32(h, idxn[i], kk, g);
        }
        {
            int t2 = tile + 2 * GRID_O; if (t2 >= NT_O) t2 = NT_O - 1;
#pragma unroll
            for (int i = 0; i < 8; i++) {
                int bidx = w * 8 + i, kk = bidx >> 2;
                int e = ((i & 3) << 4) + rr;
                idxn[i] = (kk < 4 ? src : dst)[t2 * 64 + e];
            }
        }
#pragma unroll
        for (int mt = 0; mt < 4; ++mt)
#pragma unroll
            for (int nt = 0; nt < 2; ++nt) {
                float bb = b1r[nt];
#pragma unroll
                for (int r = 0; r < 4; ++r) {
                    float v = acc1[mt][nt][r] + bb;
                    v = v > 0.f ? v : 0.f;
                    y1h[(((w * 4 + mt) * 64 + 16 * (2 * nt + ghalf) + 4 * g + r) << 3) + j7] =
                        (_Float16)v;
                }
            }
        __syncthreads();
        f32x4 acc2[4][2];
#pragma unroll
        for (int mt = 0; mt < 4; ++mt) {
            acc2[mt][0] = f32x4{0.f, 0.f, 0.f, 0.f};
            acc2[mt][1] = f32x4{0.f, 0.f, 0.f, 0.f};
        }
#pragma unroll
        for (int kk = 0; kk < 4; ++kk) {
            half8 a[4];
#pragma unroll
            for (int mt = 0; mt < 4; ++mt) a[mt] = Y1p[(kk * 4 + mt) * 64 + l];
#pragma unroll
            for (int mt = 0; mt < 4; ++mt) {
                acc2[mt][0] = MFMA16(a[mt], W2F[0][kk], acc2[mt][0]);
                acc2[mt][1] = MFMA16(a[mt], W2F[1][kk], acc2[mt][1]);
            }
        }
#pragma unroll
        for (int mt = 0; mt < 4; ++mt)
#pragma unroll
            for (int nt = 0; nt < 2; ++nt) {
                float bb = b2r[nt];
#pragma unroll
                for (int r = 0; r < 4; ++r) {
                    float v = acc2[mt][nt][r] + bb;
                    v = v > 0.f ? v : 0.f;
                    y2h[(((w * 4 + mt) * 64 + 16 * (2 * nt + ghalf) + 4 * g + r) << 3) + j7] =
                        (_Float16)v;
                }
            }
        __syncthreads();
        f32x4 acc3 = {0.f, 0.f, 0.f, 0.f};
#pragma unroll
        for (int kk = 0; kk < 4; ++kk) {
            half8 a = Y2p[(kk * 4 + w) * 64 + l];
            acc3 = MFMA16(a, W3F[kk], acc3);
        }
        if (rr < 2) {
#pragma unroll
            for (int r = 0; r < 4; ++r) {
                int m = w * 16 + 4 * g + r;
                out[(tile * 64 + m) * 2 + rr] = acc3[r] + b3r;
            }
        }
#pragma unroll
        for (int i = 0; i < 8; i++) Xp[(w * 8 + i) * 64 + l] = xt[i];
        __syncthreads();
    }
}

// --------------------------- launch ----------------------------------------

extern "C" void kernel_launch(void* const* d_in, const int* in_sizes, int n_in,
                              void* d_out, int out_size, void* d_ws, size_t ws_size,
                              hipStream_t stream) {
    const float* h   = (const float*)d_in[0];
    const int*   src = (const int*)d_in[1];
    const int*   dst = (const int*)d_in[2];
    const float* W1  = (const float*)d_in[3];
    const float* b1  = (const float*)d_in[4];
    const float* W2  = (const float*)d_in[5];
    const float* b2  = (const float*)d_in[6];
    const float* W3  = (const float*)d_in[7];
    const float* b3  = (const float*)d_in[8];
    char*  wsb = (char*)d_ws;
    float* out = (float*)d_out;
    (void)in_sizes; (void)n_in; (void)out_size;

    if (ws_size >= WS_NEED_NEW) {
        pack_w_new<<<64, 256, 0, stream>>>(W1, W2, W3, wsb);
        pq_kernel<<<512, 512, 0, stream>>>(h, b1, wsb);
        edge_kernel<<<GRID_E, 128, 0, stream>>>(src, dst, b2, b3, wsb, out);
    } else {
        pack_w_old<<<128, 256, 0, stream>>>(W1, W2, W3, wsb);
        edge_mlp_old<<<GRID_O, 256, 0, stream>>>(h, src, dst, b1, b2, b3, wsb, out);
    }
}

// Round 4
// 218.741 us; speedup vs baseline: 1.1422x; 1.1422x over previous
//
#include <hip/hip_runtime.h>
#include <hip/hip_fp16.h>

// ---------------------------------------------------------------------------
// score = relu(relu([h[src]|h[dst]]W1+b1)W2+b2)W3+b3
// NEW PATH (ws >= 51.3MB):
//   P = h@W1_top (fp16), Q = h@W1_bot + b1 (fp16)  -- per-NODE precompute
//     (pq_kernel v3: h-tile staged once in LDS per block, XOR-swizzled)
//   edge kernel v3: B-frag = relu(P16[src]+Q16[dst]) per-lane 16B gathers,
//     ALL 16 gathers staged to regs up front (concurrency!), W2 frags in LDS
//     (VGPR relief - r3's VGPR=80 showed the compiler evicting them),
//     layer3 in-register via perm3, 512B cross-wave reduce.
// FALLBACK (small ws): round-1 kernel, f32 gather path.
// ---------------------------------------------------------------------------

typedef _Float16 half8 __attribute__((ext_vector_type(8)));
typedef _Float16 half4_t __attribute__((ext_vector_type(4)));
typedef float    f32x4 __attribute__((ext_vector_type(4)));

#define MFMA16(a, b, c) __builtin_amdgcn_mfma_f32_16x16x32_f16((a), (b), (c), 0, 0, 0)

#define N_NODES_C 100000
#define N_EDGES_C 800000

// ---- new-path ws layout ----
#define W1PF_OFF  0         // 32KB  A-frags of W1_top^T
#define W1QF_OFF  32768     // 32KB  A-frags of W1_bot^T
#define W2F_OFF_N 65536     // 32KB  A-frags of W2^T
#define W3F_OFF_N 98304     // 4KB   A-frags of W3^T (perm3)
#define P16_OFF   131072
#define TBL_HALVES (N_NODES_C * 128)            // 12.8M halves
#define Q16_OFF   (P16_OFF + TBL_HALVES * 2)
#define WS_NEED_NEW ((size_t)Q16_OFF + (size_t)TBL_HALVES * 2)   // ~51.3MB

#define ET 32                       // edges per tile (edge kernel)
#define NT_E (N_EDGES_C / ET)       // 25000
#define GRID_E 1024
#define NT_N ((N_NODES_C + 63) / 64)  // 1563

// =========================== NEW PATH ======================================

// A-frag pack: frag (cm,kk): lane=16g+rr elem j -> W[32kk+8g+j][16cm+rr]
// w3f uses perm3(g,j)=4g+(j&3)+16*(j>>2) (shared by B-side built in-register).
__global__ void pack_w_new(const float* __restrict__ W1, const float* __restrict__ W2,
                           const float* __restrict__ W3, char* __restrict__ wsb) {
    int i = blockIdx.x * blockDim.x + threadIdx.x;
    _Float16* w1pf = (_Float16*)(wsb + W1PF_OFF);
    _Float16* w1qf = (_Float16*)(wsb + W1QF_OFF);
    _Float16* w2f  = (_Float16*)(wsb + W2F_OFF_N);
    _Float16* w3f  = (_Float16*)(wsb + W3F_OFF_N);
    if (i < 16384) {
        int j = i & 7, lane = (i >> 3) & 63, kk = (i >> 9) & 3, cm = i >> 11;
        int g = lane >> 4, rr = lane & 15;
        int k = 32 * kk + 8 * g + j, n = 16 * cm + rr;
        w1pf[i] = (_Float16)W1[k * 128 + n];
        w1qf[i] = (_Float16)W1[(k + 128) * 128 + n];
        w2f[i]  = (_Float16)W2[k * 128 + n];
    }
    if (i < 2048) {
        int j = i & 7, lane = (i >> 3) & 63, t = i >> 9;
        int g = lane >> 4, rr = lane & 15;
        int k = 32 * t + 4 * g + (j & 3) + 16 * (j >> 2);
        w3f[i] = (rr < 2) ? (_Float16)W3[k * 2 + rr] : (_Float16)0.0f;
    }
}

// pq v3: one 64-node tile per block. Stage h-tile (32KB f32) in LDS once;
// all 8 waves read B-frags from LDS (XOR-swizzled slots, bank-balanced).
// Wave w: table t=w>>2 (P/Q), chan-quad cmq=w&3.
__global__ __launch_bounds__(512, 4) void pq_kernel(const float* __restrict__ h,
                                                    const float* __restrict__ b1,
                                                    char* __restrict__ wsb) {
    __shared__ float4 Htile[64 * 32];   // 32KB: row r, slot s holds chunk s^(r&15)
    const int tid = threadIdx.x;
    const int w = tid >> 6, l = tid & 63, g = l >> 4, rr = l & 15;
    const int t = w >> 2, cmq = w & 3;
    const half8* wf = (const half8*)(wsb + (t ? W1QF_OFF : W1PF_OFF));
    half8 W1F[2][4];
#pragma unroll
    for (int cm = 0; cm < 2; ++cm)
#pragma unroll
        for (int kk = 0; kk < 4; ++kk)
            W1F[cm][kk] = wf[((2 * cmq + cm) * 4 + kk) * 64 + l];
    f32x4 b1v[2] = {{0.f, 0.f, 0.f, 0.f}, {0.f, 0.f, 0.f, 0.f}};
    if (t == 1) {
#pragma unroll
        for (int cm = 0; cm < 2; ++cm)
            b1v[cm] = *(const f32x4*)(b1 + 16 * (2 * cmq + cm) + 4 * g);
    }
    _Float16* tbl = (_Float16*)(wsb + (t ? Q16_OFF : P16_OFF));

    const int tile = blockIdx.x;
    // ---- stage: thread covers 4 (row,slot) pairs; coalesced global reads,
    //      swizzled ds_write (slot' = slot ^ (row&15)).
    const int slot = l & 31, rhalf = l >> 5;   // within a 2-row group
    float4 sv[4];
    int rows[4];
#pragma unroll
    for (int i = 0; i < 4; ++i) {
        int row = 8 * w + 2 * i + rhalf;
        rows[i] = row;
        int node = tile * 64 + row;
        if (node > N_NODES_C - 1) node = N_NODES_C - 1;
        sv[i] = *(const float4*)(h + (size_t)node * 128 + slot * 4);
    }
#pragma unroll
    for (int i = 0; i < 4; ++i)
        Htile[rows[i] * 32 + (slot ^ (rows[i] & 15))] = sv[i];
    __syncthreads();

    // ---- compute: B-frag (kk,ce): lane 16g+rr reads row 16ce+rr,
    //      chunks kk*8+2g, +1 (swizzle ^rr).
    f32x4 acc[2][4];
#pragma unroll
    for (int cm = 0; cm < 2; ++cm)
#pragma unroll
        for (int ce = 0; ce < 4; ++ce) acc[cm][ce] = f32x4{0.f, 0.f, 0.f, 0.f};
#pragma unroll
    for (int kk = 0; kk < 4; ++kk) {
#pragma unroll
        for (int ce = 0; ce < 4; ++ce) {
            int row = 16 * ce + rr;
            int s0 = kk * 8 + 2 * g;
            float4 fa = Htile[row * 32 + (s0 ^ rr)];
            float4 fb = Htile[row * 32 + ((s0 + 1) ^ rr)];
            half8 b;
            b[0] = (_Float16)fa.x; b[1] = (_Float16)fa.y;
            b[2] = (_Float16)fa.z; b[3] = (_Float16)fa.w;
            b[4] = (_Float16)fb.x; b[5] = (_Float16)fb.y;
            b[6] = (_Float16)fb.z; b[7] = (_Float16)fb.w;
            acc[0][ce] = MFMA16(W1F[0][kk], b, acc[0][ce]);
            acc[1][ce] = MFMA16(W1F[1][kk], b, acc[1][ce]);
        }
    }
#pragma unroll
    for (int cm = 0; cm < 2; ++cm)
#pragma unroll
        for (int ce = 0; ce < 4; ++ce) {
            int node = tile * 64 + 16 * ce + rr;
            if (node < N_NODES_C) {
                f32x4 v = acc[cm][ce] + b1v[cm];
                half4_t o;
                o[0] = (_Float16)v[0]; o[1] = (_Float16)v[1];
                o[2] = (_Float16)v[2]; o[3] = (_Float16)v[3];
                *(half4_t*)(tbl + (size_t)node * 128 + 16 * (2 * cmq + cm) + 4 * g) = o;
            }
        }
}

// Edge kernel v3: 128 thr = 2 waves; wave w owns layer-2 chans [64w,64w+64).
// W2 frags in LDS (32KB); all 16 gathers staged to regs before MFMA block.
__global__ __launch_bounds__(128, 3) void edge_kernel(
    const int* __restrict__ src, const int* __restrict__ dst,
    const float* __restrict__ b2, const float* __restrict__ b3,
    const char* __restrict__ wsb, float* __restrict__ out) {
    __shared__ half8 W2lds[2048];       // 32KB: frag f at [f*64 + lane]
    __shared__ float2 part[2][2][16];
    const int tid = threadIdx.x;
    const int w = tid >> 6, l = tid & 63, g = l >> 4, rr = l & 15;
    const half8* w2fg = (const half8*)(wsb + W2F_OFF_N);
    const half8* w3f = (const half8*)(wsb + W3F_OFF_N);
    const half8* P16 = (const half8*)(wsb + P16_OFF);   // row = 16 chunks of 16B
    const half8* Q16 = (const half8*)(wsb + Q16_OFF);

#pragma unroll
    for (int i = 0; i < 16; ++i) W2lds[i * 128 + tid] = w2fg[i * 128 + tid];

    half8 W3F[2];
    W3F[0] = w3f[(2 * w) * 64 + l];
    W3F[1] = w3f[(2 * w + 1) * 64 + l];

    half4_t b2h[4];
#pragma unroll
    for (int cm = 0; cm < 4; ++cm) {
        f32x4 bv = *(const f32x4*)(b2 + 16 * (4 * w + cm) + 4 * g);
        b2h[cm][0] = (_Float16)bv[0]; b2h[cm][1] = (_Float16)bv[1];
        b2h[cm][2] = (_Float16)bv[2]; b2h[cm][3] = (_Float16)bv[3];
    }
    const float b30 = b3[0], b31 = b3[1];

    int tile = blockIdx.x;
    int sc0 = src[tile * ET + rr],      sc1 = src[tile * ET + 16 + rr];
    int dc0 = dst[tile * ET + rr],      dc1 = dst[tile * ET + 16 + rr];
    int par = 0;
    __syncthreads();   // W2lds ready

    for (; tile < NT_E; tile += GRID_E) {
        int ntile = tile + GRID_E; if (ntile >= NT_E) ntile = NT_E - 1;
        const half8* pr0 = P16 + (size_t)sc0 * 16 + g;
        const half8* pr1 = P16 + (size_t)sc1 * 16 + g;
        const half8* qr0 = Q16 + (size_t)dc0 * 16 + g;
        const half8* qr1 = Q16 + (size_t)dc1 * 16 + g;

        // ---- stage ALL 16 gathers first (keeps 16 loads in flight)
        half8 P0[4], P1[4], Q0[4], Q1[4];
#pragma unroll
        for (int kk = 0; kk < 4; ++kk) {
            P0[kk] = pr0[4 * kk];
            Q0[kk] = qr0[4 * kk];
            P1[kk] = pr1[4 * kk];
            Q1[kk] = qr1[4 * kk];
        }
        // prefetch next-tile indices
        int sn0 = src[ntile * ET + rr], sn1 = src[ntile * ET + 16 + rr];
        int dn0 = dst[ntile * ET + rr], dn1 = dst[ntile * ET + 16 + rr];

        f32x4 acc[4][2];
#pragma unroll
        for (int cm = 0; cm < 4; ++cm) {
            acc[cm][0] = f32x4{0.f, 0.f, 0.f, 0.f};
            acc[cm][1] = f32x4{0.f, 0.f, 0.f, 0.f};
        }
        const half8 hz = {0, 0, 0, 0, 0, 0, 0, 0};
#pragma unroll
        for (int kk = 0; kk < 4; ++kk) {
            half8 bq0 = __builtin_elementwise_max(P0[kk] + Q0[kk], hz);
            half8 bq1 = __builtin_elementwise_max(P1[kk] + Q1[kk], hz);
#pragma unroll
            for (int cm = 0; cm < 4; ++cm) {
                half8 wfr = W2lds[((4 * w + cm) * 4 + kk) * 64 + l];
                acc[cm][0] = MFMA16(wfr, bq0, acc[cm][0]);
                acc[cm][1] = MFMA16(wfr, bq1, acc[cm][1]);
            }
        }

        // ---- layer 3 in-register: chans of this wave = 64w + 32tl + perm3(g,j)
        f32x4 D3[2] = {{0.f, 0.f, 0.f, 0.f}, {0.f, 0.f, 0.f, 0.f}};
#pragma unroll
        for (int tl = 0; tl < 2; ++tl)
#pragma unroll
            for (int ce = 0; ce < 2; ++ce) {
                half8 bf;
#pragma unroll
                for (int j = 0; j < 8; ++j) {
                    const int cm = 2 * tl + (j >> 2), r = j & 3;
                    float v = acc[cm][ce][r] + (float)b2h[cm][r];
                    v = v > 0.f ? v : 0.f;
                    bf[j] = (_Float16)v;
                }
                D3[ce] = MFMA16(W3F[tl], bf, D3[ce]);
            }
        // ---- cross-wave reduce (rows 0,1 live in lanes l<16, regs 0,1)
        if (w == 1 && l < 16) {
            part[par][0][rr] = make_float2(D3[0][0], D3[0][1]);
            part[par][1][rr] = make_float2(D3[1][0], D3[1][1]);
        }
        __syncthreads();
        if (w == 0 && l < 16) {
#pragma unroll
            for (int ce = 0; ce < 2; ++ce) {
                float2 pp = part[par][ce][rr];
                float2 ov;
                ov.x = D3[ce][0] + pp.x + b30;
                ov.y = D3[ce][1] + pp.y + b31;
                *(float2*)(out + (size_t)(tile * ET + 16 * ce + rr) * 2) = ov;
            }
        }
        par ^= 1;
        sc0 = sn0; sc1 = sn1; dc0 = dn0; dc1 = dn1;
    }
}

// =========================== FALLBACK (round-1, f32 gather) ================

#define NT_O   12500
#define GRID_O 512
#define OW1_OFF 0
#define OW2_OFF 65536
#define OW3_OFF 98304

__global__ void pack_w_old(const float* __restrict__ W1, const float* __restrict__ W2,
                           const float* __restrict__ W3, char* __restrict__ wsb) {
    int i = blockIdx.x * blockDim.x + threadIdx.x;
    _Float16* w1f = (_Float16*)(wsb + OW1_OFF);
    _Float16* w2f = (_Float16*)(wsb + OW2_OFF);
    _Float16* w3f = (_Float16*)(wsb + OW3_OFF);
    if (i < 32768) {
        int j = i & 7, lx = (i >> 3) & 63, kk = (i >> 9) & 7, t = i >> 12;
        int k = 32 * kk + 8 * (lx >> 4) + j, n = 16 * t + (lx & 15);
        w1f[i] = (_Float16)W1[k * 128 + n];
    }
    if (i < 16384) {
        int j = i & 7, lx = (i >> 3) & 63, kk = (i >> 9) & 3, t = i >> 11;
        int k = 32 * kk + 8 * (lx >> 4) + j, n = 16 * t + (lx & 15);
        w2f[i] = (_Float16)W2[k * 128 + n];
    }
    if (i < 2048) {
        int j = i & 7, lx = (i >> 3) & 63, kk = i >> 9;
        int k = 32 * kk + 8 * (lx >> 4) + j, n = lx & 15;
        w3f[i] = (n < 2) ? (_Float16)W3[k * 2 + n] : (_Float16)0.0f;
    }
}

__device__ inline half8 ldfrag_f32(const float* __restrict__ h, int idx, int kk, int g) {
    const float4* p = (const float4*)(h + (size_t)idx * 128 + (kk & 3) * 32 + g * 8);
    float4 a = p[0], b = p[1];
    half8 o;
    o[0] = (_Float16)a.x; o[1] = (_Float16)a.y; o[2] = (_Float16)a.z; o[3] = (_Float16)a.w;
    o[4] = (_Float16)b.x; o[5] = (_Float16)b.y; o[6] = (_Float16)b.z; o[7] = (_Float16)b.w;
    return o;
}

__global__ __launch_bounds__(256, 2) void edge_mlp_old(
    const float* __restrict__ h, const int* __restrict__ src, const int* __restrict__ dst,
    const float* __restrict__ b1, const float* __restrict__ b2, const float* __restrict__ b3,
    const char* __restrict__ wsb, float* __restrict__ out) {
    __shared__ half8 Xp [32 * 64];
    __shared__ half8 Y1p[16 * 64];
    __shared__ half8 Y2p[16 * 64];
    const int tid = threadIdx.x;
    const int w = tid >> 6, l = tid & 63;
    const int g = l >> 4, rr = l & 15;
    const int ghalf = rr >> 3, j7 = rr & 7;
    half8 W1F[2][8], W2F[2][4], W3F[4];
    {
        const half8* p1 = (const half8*)(wsb + OW1_OFF);
        const half8* p2 = (const half8*)(wsb + OW2_OFF);
        const half8* p3 = (const half8*)(wsb + OW3_OFF);
#pragma unroll
        for (int nt = 0; nt < 2; ++nt)
#pragma unroll
            for (int kk = 0; kk < 8; ++kk) W1F[nt][kk] = p1[((w * 2 + nt) * 8 + kk) * 64 + l];
#pragma unroll
        for (int nt = 0; nt < 2; ++nt)
#pragma unroll
            for (int kk = 0; kk < 4; ++kk) W2F[nt][kk] = p2[((w * 2 + nt) * 4 + kk) * 64 + l];
#pragma unroll
        for (int kk = 0; kk < 4; ++kk) W3F[kk] = p3[kk * 64 + l];
    }
    float b1r[2], b2r[2];
    b1r[0] = b1[w * 32 + rr];      b1r[1] = b1[w * 32 + 16 + rr];
    b2r[0] = b2[w * 32 + rr];      b2r[1] = b2[w * 32 + 16 + rr];
    const float b3r = (rr < 2) ? b3[rr] : 0.0f;
    _Float16* y1h = (_Float16*)Y1p;
    _Float16* y2h = (_Float16*)Y2p;
    int   idxn[8];
    half8 xt[8];
    int tile = blockIdx.x;
#pragma unroll
    for (int i = 0; i < 8; i++) {
        int bidx = w * 8 + i, kk = bidx >> 2;
        int e = ((i & 3) << 4) + rr;
        int id = (kk < 4 ? src : dst)[tile * 64 + e];
        xt[i] = ldfrag_f32(h, id, kk, g);
    }
#pragma unroll
    for (int i = 0; i < 8; i++) Xp[(w * 8 + i) * 64 + l] = xt[i];
    {
        int t1 = tile + GRID_O; if (t1 >= NT_O) t1 = NT_O - 1;
#pragma unroll
        for (int i = 0; i < 8; i++) {
            int bidx = w * 8 + i, kk = bidx >> 2;
            int e = ((i & 3) << 4) + rr;
            idxn[i] = (kk < 4 ? src : dst)[t1 * 64 + e];
        }
    }
    __syncthreads();
    for (; tile < NT_O; tile += GRID_O) {
        f32x4 acc1[4][2];
#pragma unroll
        for (int mt = 0; mt < 4; ++mt) {
            acc1[mt][0] = f32x4{0.f, 0.f, 0.f, 0.f};
            acc1[mt][1] = f32x4{0.f, 0.f, 0.f, 0.f};
        }
#pragma unroll
        for (int kk = 0; kk < 8; ++kk) {
            half8 a[4];
#pragma unroll
            for (int mt = 0; mt < 4; ++mt) a[mt] = Xp[(kk * 4 + mt) * 64 + l];
#pragma unroll
            for (int mt = 0; mt < 4; ++mt) {
                acc1[mt][0] = MFMA16(a[mt], W1F[0][kk], acc1[mt][0]);
                acc1[mt][1] = MFMA16(a[mt], W1F[1][kk], acc1[mt][1]);
            }
        }
#pragma unroll
        for (int i = 0; i < 8; i++) {
            int kk = (w * 8 + i) >> 2;
            xt[i] = ldfrag_f32(h, idxn[i], kk, g);
        }
        {
            int t2 = tile + 2 * GRID_O; if (t2 >= NT_O) t2 = NT_O - 1;
#pragma unroll
            for (int i = 0; i < 8; i++) {
                int bidx = w * 8 + i, kk = bidx >> 2;
                int e = ((i & 3) << 4) + rr;
                idxn[i] = (kk < 4 ? src : dst)[t2 * 64 + e];
            }
        }
#pragma unroll
        for (int mt = 0; mt < 4; ++mt)
#pragma unroll
            for (int nt = 0; nt < 2; ++nt) {
                float bb = b1r[nt];
#pragma unroll
                for (int r = 0; r < 4; ++r) {
                    float v = acc1[mt][nt][r] + bb;
                    v = v > 0.f ? v : 0.f;
                    y1h[(((w * 4 + mt) * 64 + 16 * (2 * nt + ghalf) + 4 * g + r) << 3) + j7] =
                        (_Float16)v;
                }
            }
        __syncthreads();
        f32x4 acc2[4][2];
#pragma unroll
        for (int mt = 0; mt < 4; ++mt) {
            acc2[mt][0] = f32x4{0.f, 0.f, 0.f, 0.f};
            acc2[mt][1] = f32x4{0.f, 0.f, 0.f, 0.f};
        }
#pragma unroll
        for (int kk = 0; kk < 4; ++kk) {
            half8 a[4];
#pragma unroll
            for (int mt = 0; mt < 4; ++mt) a[mt] = Y1p[(kk * 4 + mt) * 64 + l];
#pragma unroll
            for (int mt = 0; mt < 4; ++mt) {
                acc2[mt][0] = MFMA16(a[mt], W2F[0][kk], acc2[mt][0]);
                acc2[mt][1] = MFMA16(a[mt], W2F[1][kk], acc2[mt][1]);
            }
        }
#pragma unroll
        for (int mt = 0; mt < 4; ++mt)
#pragma unroll
            for (int nt = 0; nt < 2; ++nt) {
                float bb = b2r[nt];
#pragma unroll
                for (int r = 0; r < 4; ++r) {
                    float v = acc2[mt][nt][r] + bb;
                    v = v > 0.f ? v : 0.f;
                    y2h[(((w * 4 + mt) * 64 + 16 * (2 * nt + ghalf) + 4 * g + r) << 3) + j7] =
                        (_Float16)v;
                }
            }
        __syncthreads();
        f32x4 acc3 = {0.f, 0.f, 0.f, 0.f};
#pragma unroll
        for (int kk = 0; kk < 4; ++kk) {
            half8 a = Y2p[(kk * 4 + w) * 64 + l];
            acc3 = MFMA16(a, W3F[kk], acc3);
        }
        if (rr < 2) {
#pragma unroll
            for (int r = 0; r < 4; ++r) {
                int m = w * 16 + 4 * g + r;
                out[(tile * 64 + m) * 2 + rr] = acc3[r] + b3r;
            }
        }
#pragma unroll
        for (int i = 0; i < 8; i++) Xp[(w * 8 + i) * 64 + l] = xt[i];
        __syncthreads();
    }
}

// --------------------------- launch ----------------------------------------

extern "C" void kernel_launch(void* const* d_in, const int* in_sizes, int n_in,
                              void* d_out, int out_size, void* d_ws, size_t ws_size,
                              hipStream_t stream) {
    const float* h   = (const float*)d_in[0];
    const int*   src = (const int*)d_in[1];
    const int*   dst = (const int*)d_in[2];
    const float* W1  = (const float*)d_in[3];
    const float* b1  = (const float*)d_in[4];
    const float* W2  = (const float*)d_in[5];
    const float* b2  = (const float*)d_in[6];
    const float* W3  = (const float*)d_in[7];
    const float* b3  = (const float*)d_in[8];
    char*  wsb = (char*)d_ws;
    float* out = (float*)d_out;
    (void)in_sizes; (void)n_in; (void)out_size;

    if (ws_size >= WS_NEED_NEW) {
        pack_w_new<<<64, 256, 0, stream>>>(W1, W2, W3, wsb);
        pq_kernel<<<NT_N, 512, 0, stream>>>(h, b1, wsb);
        edge_kernel<<<GRID_E, 128, 0, stream>>>(src, dst, b2, b3, wsb, out);
    } else {
        pack_w_old<<<128, 256, 0, stream>>>(W1, W2, W3, wsb);
        edge_mlp_old<<<GRID_O, 256, 0, stream>>>(h, src, dst, b1, b2, b3, wsb, out);
    }
}

// Round 5
// 215.785 us; speedup vs baseline: 1.1579x; 1.0137x over previous
//
#include <hip/hip_runtime.h>
#include <hip/hip_fp16.h>

// ---------------------------------------------------------------------------
// score = relu(relu([h[src]|h[dst]]W1+b1)W2+b2)W3+b3
// NEW PATH (ws >= 51.3MB):
//   P = h@W1_top (fp16), Q = h@W1_bot + b1 (fp16)  -- per-NODE precompute
//   edge kernel v5: double-buffered register gather pipeline (sets A/B,
//     unroll x2, sched_barrier(0) pins issue order), launch_bounds(128,2)
//     so the allocator may hold both sets (v4's bounds(128,3) capped VGPR
//     at ~170 and the scheduler serialized every gather), W2 frags in LDS.
// FALLBACK (small ws): round-1 kernel, f32 gather path.
// ---------------------------------------------------------------------------

typedef _Float16 half8 __attribute__((ext_vector_type(8)));
typedef _Float16 half4_t __attribute__((ext_vector_type(4)));
typedef float    f32x4 __attribute__((ext_vector_type(4)));

#define MFMA16(a, b, c) __builtin_amdgcn_mfma_f32_16x16x32_f16((a), (b), (c), 0, 0, 0)

#define N_NODES_C 100000
#define N_EDGES_C 800000

// ---- new-path ws layout ----
#define W1PF_OFF  0         // 32KB  A-frags of W1_top^T
#define W1QF_OFF  32768     // 32KB  A-frags of W1_bot^T
#define W2F_OFF_N 65536     // 32KB  A-frags of W2^T
#define W3F_OFF_N 98304     // 4KB   A-frags of W3^T (perm3)
#define P16_OFF   131072
#define TBL_HALVES (N_NODES_C * 128)            // 12.8M halves
#define Q16_OFF   (P16_OFF + TBL_HALVES * 2)
#define WS_NEED_NEW ((size_t)Q16_OFF + (size_t)TBL_HALVES * 2)   // ~51.3MB

#define ET 32                       // edges per tile (edge kernel)
#define NT_E (N_EDGES_C / ET)       // 25000
#define GRID_E 1024
#define NT_N ((N_NODES_C + 63) / 64)  // 1563

// =========================== NEW PATH ======================================

// A-frag pack: frag (cm,kk): lane=16g+rr elem j -> W[32kk+8g+j][16cm+rr]
// w3f uses perm3(g,j)=4g+(j&3)+16*(j>>2) (shared by B-side built in-register).
__global__ void pack_w_new(const float* __restrict__ W1, const float* __restrict__ W2,
                           const float* __restrict__ W3, char* __restrict__ wsb) {
    int i = blockIdx.x * blockDim.x + threadIdx.x;
    _Float16* w1pf = (_Float16*)(wsb + W1PF_OFF);
    _Float16* w1qf = (_Float16*)(wsb + W1QF_OFF);
    _Float16* w2f  = (_Float16*)(wsb + W2F_OFF_N);
    _Float16* w3f  = (_Float16*)(wsb + W3F_OFF_N);
    if (i < 16384) {
        int j = i & 7, lane = (i >> 3) & 63, kk = (i >> 9) & 3, cm = i >> 11;
        int g = lane >> 4, rr = lane & 15;
        int k = 32 * kk + 8 * g + j, n = 16 * cm + rr;
        w1pf[i] = (_Float16)W1[k * 128 + n];
        w1qf[i] = (_Float16)W1[(k + 128) * 128 + n];
        w2f[i]  = (_Float16)W2[k * 128 + n];
    }
    if (i < 2048) {
        int j = i & 7, lane = (i >> 3) & 63, t = i >> 9;
        int g = lane >> 4, rr = lane & 15;
        int k = 32 * t + 4 * g + (j & 3) + 16 * (j >> 2);
        w3f[i] = (rr < 2) ? (_Float16)W3[k * 2 + rr] : (_Float16)0.0f;
    }
}

// pq: one 64-node tile per block. Stage h-tile (32KB f32) in LDS once
// (XOR-swizzled slots); 8 waves: table t=w>>2 (P/Q), chan-quad cmq=w&3.
__global__ __launch_bounds__(512, 4) void pq_kernel(const float* __restrict__ h,
                                                    const float* __restrict__ b1,
                                                    char* __restrict__ wsb) {
    __shared__ float4 Htile[64 * 32];   // 32KB: row r, slot s holds chunk s^(r&15)
    const int tid = threadIdx.x;
    const int w = tid >> 6, l = tid & 63, g = l >> 4, rr = l & 15;
    const int t = w >> 2, cmq = w & 3;
    const half8* wf = (const half8*)(wsb + (t ? W1QF_OFF : W1PF_OFF));
    half8 W1F[2][4];
#pragma unroll
    for (int cm = 0; cm < 2; ++cm)
#pragma unroll
        for (int kk = 0; kk < 4; ++kk)
            W1F[cm][kk] = wf[((2 * cmq + cm) * 4 + kk) * 64 + l];
    f32x4 b1v[2] = {{0.f, 0.f, 0.f, 0.f}, {0.f, 0.f, 0.f, 0.f}};
    if (t == 1) {
#pragma unroll
        for (int cm = 0; cm < 2; ++cm)
            b1v[cm] = *(const f32x4*)(b1 + 16 * (2 * cmq + cm) + 4 * g);
    }
    _Float16* tbl = (_Float16*)(wsb + (t ? Q16_OFF : P16_OFF));

    const int tile = blockIdx.x;
    const int slot = l & 31, rhalf = l >> 5;
    float4 sv[4];
    int rows[4];
#pragma unroll
    for (int i = 0; i < 4; ++i) {
        int row = 8 * w + 2 * i + rhalf;
        rows[i] = row;
        int node = tile * 64 + row;
        if (node > N_NODES_C - 1) node = N_NODES_C - 1;
        sv[i] = *(const float4*)(h + (size_t)node * 128 + slot * 4);
    }
#pragma unroll
    for (int i = 0; i < 4; ++i)
        Htile[rows[i] * 32 + (slot ^ (rows[i] & 15))] = sv[i];
    __syncthreads();

    f32x4 acc[2][4];
#pragma unroll
    for (int cm = 0; cm < 2; ++cm)
#pragma unroll
        for (int ce = 0; ce < 4; ++ce) acc[cm][ce] = f32x4{0.f, 0.f, 0.f, 0.f};
#pragma unroll
    for (int kk = 0; kk < 4; ++kk) {
#pragma unroll
        for (int ce = 0; ce < 4; ++ce) {
            int row = 16 * ce + rr;
            int s0 = kk * 8 + 2 * g;
            float4 fa = Htile[row * 32 + (s0 ^ rr)];
            float4 fb = Htile[row * 32 + ((s0 + 1) ^ rr)];
            half8 b;
            b[0] = (_Float16)fa.x; b[1] = (_Float16)fa.y;
            b[2] = (_Float16)fa.z; b[3] = (_Float16)fa.w;
            b[4] = (_Float16)fb.x; b[5] = (_Float16)fb.y;
            b[6] = (_Float16)fb.z; b[7] = (_Float16)fb.w;
            acc[0][ce] = MFMA16(W1F[0][kk], b, acc[0][ce]);
            acc[1][ce] = MFMA16(W1F[1][kk], b, acc[1][ce]);
        }
    }
#pragma unroll
    for (int cm = 0; cm < 2; ++cm)
#pragma unroll
        for (int ce = 0; ce < 4; ++ce) {
            int node = tile * 64 + 16 * ce + rr;
            if (node < N_NODES_C) {
                f32x4 v = acc[cm][ce] + b1v[cm];
                half4_t o;
                o[0] = (_Float16)v[0]; o[1] = (_Float16)v[1];
                o[2] = (_Float16)v[2]; o[3] = (_Float16)v[3];
                *(half4_t*)(tbl + (size_t)node * 128 + 16 * (2 * cmq + cm) + 4 * g) = o;
            }
        }
}

// ---------------- edge kernel v5: double-buffered gather pipeline ----------

#define IDXLOAD(T, s0, s1, d0, d1)                            \
    {                                                          \
        int tt = (T); if (tt >= NT_E) tt = NT_E - 1;           \
        s0 = src[tt * ET + rr];  s1 = src[tt * ET + 16 + rr];  \
        d0 = dst[tt * ET + rr];  d1 = dst[tt * ET + 16 + rr];  \
    }

#define LOADSET(SP0, SP1, SQ0, SQ1, s0, s1, d0, d1)            \
    {                                                          \
        const half8* pr0 = P16 + (size_t)(s0) * 16 + g;        \
        const half8* pr1 = P16 + (size_t)(s1) * 16 + g;        \
        const half8* qr0 = Q16 + (size_t)(d0) * 16 + g;        \
        const half8* qr1 = Q16 + (size_t)(d1) * 16 + g;        \
        _Pragma("unroll")                                      \
        for (int kk = 0; kk < 4; ++kk) {                       \
            SP0[kk] = pr0[4 * kk];  SQ0[kk] = qr0[4 * kk];     \
            SP1[kk] = pr1[4 * kk];  SQ1[kk] = qr1[4 * kk];     \
        }                                                      \
    }

#define COMPUTE_STORE(SP0, SP1, SQ0, SQ1, TILE)                                 \
    {                                                                           \
        f32x4 acc[4][2];                                                        \
        _Pragma("unroll")                                                       \
        for (int cm = 0; cm < 4; ++cm) {                                        \
            acc[cm][0] = f32x4{0.f, 0.f, 0.f, 0.f};                             \
            acc[cm][1] = f32x4{0.f, 0.f, 0.f, 0.f};                             \
        }                                                                       \
        const half8 hz = {0, 0, 0, 0, 0, 0, 0, 0};                              \
        _Pragma("unroll")                                                       \
        for (int kk = 0; kk < 4; ++kk) {                                        \
            half8 bq0 = __builtin_elementwise_max(SP0[kk] + SQ0[kk], hz);       \
            half8 bq1 = __builtin_elementwise_max(SP1[kk] + SQ1[kk], hz);       \
            _Pragma("unroll")                                                   \
            for (int cm = 0; cm < 4; ++cm) {                                    \
                half8 wfr = W2lds[((4 * w + cm) * 4 + kk) * 64 + l];            \
                acc[cm][0] = MFMA16(wfr, bq0, acc[cm][0]);                      \
                acc[cm][1] = MFMA16(wfr, bq1, acc[cm][1]);                      \
            }                                                                   \
        }                                                                       \
        f32x4 D3[2] = {{0.f, 0.f, 0.f, 0.f}, {0.f, 0.f, 0.f, 0.f}};             \
        _Pragma("unroll")                                                       \
        for (int tl = 0; tl < 2; ++tl)                                          \
            _Pragma("unroll")                                                   \
            for (int ce = 0; ce < 2; ++ce) {                                    \
                half8 bf;                                                       \
                _Pragma("unroll")                                               \
                for (int j = 0; j < 8; ++j) {                                   \
                    const int cm = 2 * tl + (j >> 2), r = j & 3;                \
                    float v = acc[cm][ce][r] + (float)b2h[cm][r];               \
                    v = v > 0.f ? v : 0.f;                                      \
                    bf[j] = (_Float16)v;                                        \
                }                                                               \
                D3[ce] = MFMA16(W3F[tl], bf, D3[ce]);                           \
            }                                                                   \
        if (w == 1 && l < 16) {                                                 \
            part[par][0][rr] = make_float2(D3[0][0], D3[0][1]);                 \
            part[par][1][rr] = make_float2(D3[1][0], D3[1][1]);                 \
        }                                                                       \
        __syncthreads();                                                        \
        if (w == 0 && l < 16) {                                                 \
            _Pragma("unroll")                                                   \
            for (int ce = 0; ce < 2; ++ce) {                                    \
                float2 pp = part[par][ce][rr];                                  \
                float2 ov;                                                      \
                ov.x = D3[ce][0] + pp.x + b30;                                  \
                ov.y = D3[ce][1] + pp.y + b31;                                  \
                *(float2*)(out + (size_t)((TILE) * ET + 16 * ce + rr) * 2) = ov;\
            }                                                                   \
        }                                                                       \
        par ^= 1;                                                               \
    }

__global__ __launch_bounds__(128, 2) void edge_kernel(
    const int* __restrict__ src, const int* __restrict__ dst,
    const float* __restrict__ b2, const float* __restrict__ b3,
    const char* __restrict__ wsb, float* __restrict__ out) {
    __shared__ half8 W2lds[2048];       // 32KB: frag f at [f*64 + lane]
    __shared__ float2 part[2][2][16];
    const int tid = threadIdx.x;
    const int w = tid >> 6, l = tid & 63, g = l >> 4, rr = l & 15;
    const half8* w2fg = (const half8*)(wsb + W2F_OFF_N);
    const half8* w3f = (const half8*)(wsb + W3F_OFF_N);
    const half8* P16 = (const half8*)(wsb + P16_OFF);   // row = 16 chunks of 16B
    const half8* Q16 = (const half8*)(wsb + Q16_OFF);

#pragma unroll
    for (int i = 0; i < 16; ++i) W2lds[i * 128 + tid] = w2fg[i * 128 + tid];

    half8 W3F[2];
    W3F[0] = w3f[(2 * w) * 64 + l];
    W3F[1] = w3f[(2 * w + 1) * 64 + l];

    half4_t b2h[4];
#pragma unroll
    for (int cm = 0; cm < 4; ++cm) {
        f32x4 bv = *(const f32x4*)(b2 + 16 * (4 * w + cm) + 4 * g);
        b2h[cm][0] = (_Float16)bv[0]; b2h[cm][1] = (_Float16)bv[1];
        b2h[cm][2] = (_Float16)bv[2]; b2h[cm][3] = (_Float16)bv[3];
    }
    const float b30 = b3[0], b31 = b3[1];
    int par = 0;

    // register double-buffer sets
    half8 PA0[4], PA1[4], QA0[4], QA1[4];
    half8 PB0[4], PB1[4], QB0[4], QB1[4];
    int ia0, ia1, ja0, ja1;     // indices currently being/about-to-be loaded
    int ib0, ib1, jb0, jb1;

    int tile = blockIdx.x;
    IDXLOAD(tile, ia0, ia1, ja0, ja1);
    LOADSET(PA0, PA1, QA0, QA1, ia0, ia1, ja0, ja1);   // data(tile) -> A
    IDXLOAD(tile + GRID_E, ib0, ib1, jb0, jb1);        // idx(tile+G)
    __syncthreads();   // W2lds ready

    for (;;) {
        // A = data(tile); iB = idx(tile+G)
        LOADSET(PB0, PB1, QB0, QB1, ib0, ib1, jb0, jb1);   // issue gathers t+G
        __builtin_amdgcn_sched_barrier(0);                  // pin issue order
        IDXLOAD(tile + 2 * GRID_E, ia0, ia1, ja0, ja1);     // idx(t+2G)
        COMPUTE_STORE(PA0, PA1, QA0, QA1, tile);
        tile += GRID_E;
        if (tile >= NT_E) break;

        // B = data(tile); iA = idx(tile+G)
        LOADSET(PA0, PA1, QA0, QA1, ia0, ia1, ja0, ja1);
        __builtin_amdgcn_sched_barrier(0);
        IDXLOAD(tile + 2 * GRID_E, ib0, ib1, jb0, jb1);
        COMPUTE_STORE(PB0, PB1, QB0, QB1, tile);
        tile += GRID_E;
        if (tile >= NT_E) break;
    }
}

// =========================== FALLBACK (round-1, f32 gather) ================

#define NT_O   12500
#define GRID_O 512
#define OW1_OFF 0
#define OW2_OFF 65536
#define OW3_OFF 98304

__global__ void pack_w_old(const float* __restrict__ W1, const float* __restrict__ W2,
                           const float* __restrict__ W3, char* __restrict__ wsb) {
    int i = blockIdx.x * blockDim.x + threadIdx.x;
    _Float16* w1f = (_Float16*)(wsb + OW1_OFF);
    _Float16* w2f = (_Float16*)(wsb + OW2_OFF);
    _Float16* w3f = (_Float16*)(wsb + OW3_OFF);
    if (i < 32768) {
        int j = i & 7, lx = (i >> 3) & 63, kk = (i >> 9) & 7, t = i >> 12;
        int k = 32 * kk + 8 * (lx >> 4) + j, n = 16 * t + (lx & 15);
        w1f[i] = (_Float16)W1[k * 128 + n];
    }
    if (i < 16384) {
        int j = i & 7, lx = (i >> 3) & 63, kk = (i >> 9) & 3, t = i >> 11;
        int k = 32 * kk + 8 * (lx >> 4) + j, n = 16 * t + (lx & 15);
        w2f[i] = (_Float16)W2[k * 128 + n];
    }
    if (i < 2048) {
        int j = i & 7, lx = (i >> 3) & 63, kk = i >> 9;
        int k = 32 * kk + 8 * (lx >> 4) + j, n = lx & 15;
        w3f[i] = (n < 2) ? (_Float16)W3[k * 2 + n] : (_Float16)0.0f;
    }
}

__device__ inline half8 ldfrag_f32(const float* __restrict__ h, int idx, int kk, int g) {
    const float4* p = (const float4*)(h + (size_t)idx * 128 + (kk & 3) * 32 + g * 8);
    float4 a = p[0], b = p[1];
    half8 o;
    o[0] = (_Float16)a.x; o[1] = (_Float16)a.y; o[2] = (_Float16)a.z; o[3] = (_Float16)a.w;
    o[4] = (_Float16)b.x; o[5] = (_Float16)b.y; o[6] = (_Float16)b.z; o[7] = (_Float16)b.w;
    return o;
}

__global__ __launch_bounds__(256, 2) void edge_mlp_old(
    const float* __restrict__ h, const int* __restrict__ src, const int* __restrict__ dst,
    const float* __restrict__ b1, const float* __restrict__ b2, const float* __restrict__ b3,
    const char* __restrict__ wsb, float* __restrict__ out) {
    __shared__ half8 Xp [32 * 64];
    __shared__ half8 Y1p[16 * 64];
    __shared__ half8 Y2p[16 * 64];
    const int tid = threadIdx.x;
    const int w = tid >> 6, l = tid & 63;
    const int g = l >> 4, rr = l & 15;
    const int ghalf = rr >> 3, j7 = rr & 7;
    half8 W1F[2][8], W2F[2][4], W3F[4];
    {
        const half8* p1 = (const half8*)(wsb + OW1_OFF);
        const half8* p2 = (const half8*)(wsb + OW2_OFF);
        const half8* p3 = (const half8*)(wsb + OW3_OFF);
#pragma unroll
        for (int nt = 0; nt < 2; ++nt)
#pragma unroll
            for (int kk = 0; kk < 8; ++kk) W1F[nt][kk] = p1[((w * 2 + nt) * 8 + kk) * 64 + l];
#pragma unroll
        for (int nt = 0; nt < 2; ++nt)
#pragma unroll
            for (int kk = 0; kk < 4; ++kk) W2F[nt][kk] = p2[((w * 2 + nt) * 4 + kk) * 64 + l];
#pragma unroll
        for (int kk = 0; kk < 4; ++kk) W3F[kk] = p3[kk * 64 + l];
    }
    float b1r[2], b2r[2];
    b1r[0] = b1[w * 32 + rr];      b1r[1] = b1[w * 32 + 16 + rr];
    b2r[0] = b2[w * 32 + rr];      b2r[1] = b2[w * 32 + 16 + rr];
    const float b3r = (rr < 2) ? b3[rr] : 0.0f;
    _Float16* y1h = (_Float16*)Y1p;
    _Float16* y2h = (_Float16*)Y2p;
    int   idxn[8];
    half8 xt[8];
    int tile = blockIdx.x;
#pragma unroll
    for (int i = 0; i < 8; i++) {
        int bidx = w * 8 + i, kk = bidx >> 2;
        int e = ((i & 3) << 4) + rr;
        int id = (kk < 4 ? src : dst)[tile * 64 + e];
        xt[i] = ldfrag_f32(h, id, kk, g);
    }
#pragma unroll
    for (int i = 0; i < 8; i++) Xp[(w * 8 + i) * 64 + l] = xt[i];
    {
        int t1 = tile + GRID_O; if (t1 >= NT_O) t1 = NT_O - 1;
#pragma unroll
        for (int i = 0; i < 8; i++) {
            int bidx = w * 8 + i, kk = bidx >> 2;
            int e = ((i & 3) << 4) + rr;
            idxn[i] = (kk < 4 ? src : dst)[t1 * 64 + e];
        }
    }
    __syncthreads();
    for (; tile < NT_O; tile += GRID_O) {
        f32x4 acc1[4][2];
#pragma unroll
        for (int mt = 0; mt < 4; ++mt) {
            acc1[mt][0] = f32x4{0.f, 0.f, 0.f, 0.f};
            acc1[mt][1] = f32x4{0.f, 0.f, 0.f, 0.f};
        }
#pragma unroll
        for (int kk = 0; kk < 8; ++kk) {
            half8 a[4];
#pragma unroll
            for (int mt = 0; mt < 4; ++mt) a[mt] = Xp[(kk * 4 + mt) * 64 + l];
#pragma unroll
            for (int mt = 0; mt < 4; ++mt) {
                acc1[mt][0] = MFMA16(a[mt], W1F[0][kk], acc1[mt][0]);
                acc1[mt][1] = MFMA16(a[mt], W1F[1][kk], acc1[mt][1]);
            }
        }
#pragma unroll
        for (int i = 0; i < 8; i++) {
            int kk = (w * 8 + i) >> 2;
            xt[i] = ldfrag_f32(h, idxn[i], kk, g);
        }
        {
            int t2 = tile + 2 * GRID_O; if (t2 >= NT_O) t2 = NT_O - 1;
#pragma unroll
            for (int i = 0; i < 8; i++) {
                int bidx = w * 8 + i, kk = bidx >> 2;
                int e = ((i & 3) << 4) + rr;
                idxn[i] = (kk < 4 ? src : dst)[t2 * 64 + e];
            }
        }
#pragma unroll
        for (int mt = 0; mt < 4; ++mt)
#pragma unroll
            for (int nt = 0; nt < 2; ++nt) {
                float bb = b1r[nt];
#pragma unroll
                for (int r = 0; r < 4; ++r) {
                    float v = acc1[mt][nt][r] + bb;
                    v = v > 0.f ? v : 0.f;
                    y1h[(((w * 4 + mt) * 64 + 16 * (2 * nt + ghalf) + 4 * g + r) << 3) + j7] =
                        (_Float16)v;
                }
            }
        __syncthreads();
        f32x4 acc2[4][2];
#pragma unroll
        for (int mt = 0; mt < 4; ++mt) {
            acc2[mt][0] = f32x4{0.f, 0.f, 0.f, 0.f};
            acc2[mt][1] = f32x4{0.f, 0.f, 0.f, 0.f};
        }
#pragma unroll
        for (int kk = 0; kk < 4; ++kk) {
            half8 a[4];
#pragma unroll
            for (int mt = 0; mt < 4; ++mt) a[mt] = Y1p[(kk * 4 + mt) * 64 + l];
#pragma unroll
            for (int mt = 0; mt < 4; ++mt) {
                acc2[mt][0] = MFMA16(a[mt], W2F[0][kk], acc2[mt][0]);
                acc2[mt][1] = MFMA16(a[mt], W2F[1][kk], acc2[mt][1]);
            }
        }
#pragma unroll
        for (int mt = 0; mt < 4; ++mt)
#pragma unroll
            for (int nt = 0; nt < 2; ++nt) {
                float bb = b2r[nt];
#pragma unroll
                for (int r = 0; r < 4; ++r) {
                    float v = acc2[mt][nt][r] + bb;
                    v = v > 0.f ? v : 0.f;
                    y2h[(((w * 4 + mt) * 64 + 16 * (2 * nt + ghalf) + 4 * g + r) << 3) + j7] =
                        (_Float16)v;
                }
            }
        __syncthreads();
        f32x4 acc3 = {0.f, 0.f, 0.f, 0.f};
#pragma unroll
        for (int kk = 0; kk < 4; ++kk) {
            half8 a = Y2p[(kk * 4 + w) * 64 + l];
            acc3 = MFMA16(a, W3F[kk], acc3);
        }
        if (rr < 2) {
#pragma unroll
            for (int r = 0; r < 4; ++r) {
                int m = w * 16 + 4 * g + r;
                out[(tile * 64 + m) * 2 + rr] = acc3[r] + b3r;
            }
        }
#pragma unroll
        for (int i = 0; i < 8; i++) Xp[(w * 8 + i) * 64 + l] = xt[i];
        __syncthreads();
    }
}

// --------------------------- launch ----------------------------------------

extern "C" void kernel_launch(void* const* d_in, const int* in_sizes, int n_in,
                              void* d_out, int out_size, void* d_ws, size_t ws_size,
                              hipStream_t stream) {
    const float* h   = (const float*)d_in[0];
    const int*   src = (const int*)d_in[1];
    const int*   dst = (const int*)d_in[2];
    const float* W1  = (const float*)d_in[3];
    const float* b1  = (const float*)d_in[4];
    const float* W2  = (const float*)d_in[5];
    const float* b2  = (const float*)d_in[6];
    const float* W3  = (const float*)d_in[7];
    const float* b3  = (const float*)d_in[8];
    char*  wsb = (char*)d_ws;
    float* out = (float*)d_out;
    (void)in_sizes; (void)n_in; (void)out_size;

    if (ws_size >= WS_NEED_NEW) {
        pack_w_new<<<64, 256, 0, stream>>>(W1, W2, W3, wsb);
        pq_kernel<<<NT_N, 512, 0, stream>>>(h, b1, wsb);
        edge_kernel<<<GRID_E, 128, 0, stream>>>(src, dst, b2, b3, wsb, out);
    } else {
        pack_w_old<<<128, 256, 0, stream>>>(W1, W2, W3, wsb);
        edge_mlp_old<<<GRID_O, 256, 0, stream>>>(h, src, dst, b1, b2, b3, wsb, out);
    }
}